// Round 2
// baseline (711.310 us; speedup 1.0000x reference)
//
#include <hip/hip_runtime.h>
#include <cstdio>

// VQ nearest-codebook, round 2.
// Pipeline: prep(cb->bf16,c2) ; convx(x->bf16) ; main(m97-style 128x128 MFMA
// GEMM, fused per-128-code argmin -> 8 candidates/query) ; reduce(merge 8,
// flag gap<TAU) ; refine(exact fp64 re-scan, coalesced row reads) ; gather.

typedef short short8 __attribute__((ext_vector_type(8)));
typedef float f32x4 __attribute__((ext_vector_type(4)));

#define KDIM 512
#define NCODES 1024
#define NQ 65536
#define TAU_S 0.30f

// ---- workspace layout (bytes) ----
#define WS_XB    0ull                         // bf16 x [65536][512]      67108864
#define WS_CBB   67108864ull                  // bf16 cb [1024][512]       1048576
#define WS_C2H   68157440ull                  // float 0.5||c||^2 [1024]
#define WS_C2D   68161536ull                  // double 0.5||c||^2 [1024]
#define WS_CAND1 68169728ull                  // float  [65536][8]
#define WS_CAND2 70266880ull                  // float  [65536][8]
#define WS_CANDC 72364032ull                  // int    [65536][8]
#define WS_IDX   74461184ull                  // int    [65536]
#define WS_LIST  74723328ull                  // int    [65536]
#define WS_CTR   74985472ull                  // int
#define WS_NEED  (WS_CTR + 4ull)

__device__ __forceinline__ unsigned short f2bf(float f) {
  unsigned u = __builtin_bit_cast(unsigned, f);
  u += 0x7fffu + ((u >> 16) & 1u);            // RNE
  return (unsigned short)(u >> 16);
}

__device__ __forceinline__ void async16(const void* g, void* l) {
  __builtin_amdgcn_global_load_lds(
      (const __attribute__((address_space(1))) void*)g,
      (__attribute__((address_space(3))) void*)l, 16, 0, 0);
}

// ---------------- prep: codebook -> bf16 row-major + 0.5||c||^2 ----------------
__global__ __launch_bounds__(256) void vq_prep(const float* __restrict__ cb,
                                               unsigned short* __restrict__ cbb,
                                               float* __restrict__ c2h,
                                               double* __restrict__ c2d) {
  int lane = threadIdx.x & 63;
  int row = blockIdx.x * 4 + (threadIdx.x >> 6);
  const float4* src = (const float4*)(cb + (size_t)row * KDIM);
  float4 u = src[lane * 2], v = src[lane * 2 + 1];
  double p = (double)u.x * u.x + (double)u.y * u.y + (double)u.z * u.z + (double)u.w * u.w +
             (double)v.x * v.x + (double)v.y * v.y + (double)v.z * v.z + (double)v.w * v.w;
#pragma unroll
  for (int m = 1; m < 64; m <<= 1) p += __shfl_xor(p, m);
  if (lane == 0) { c2h[row] = (float)(0.5 * p); c2d[row] = 0.5 * p; }
  unsigned r0 = f2bf(u.x) | ((unsigned)f2bf(u.y) << 16);
  unsigned r1 = f2bf(u.z) | ((unsigned)f2bf(u.w) << 16);
  unsigned r2 = f2bf(v.x) | ((unsigned)f2bf(v.y) << 16);
  unsigned r3 = f2bf(v.z) | ((unsigned)f2bf(v.w) << 16);
  *(int4*)(cbb + (size_t)row * KDIM + lane * 8) = make_int4((int)r0, (int)r1, (int)r2, (int)r3);
}

// ---------------- convx: x fp32 -> bf16 ----------------
__global__ __launch_bounds__(256) void vq_convx(const float4* __restrict__ x4,
                                                int4* __restrict__ xb4) {
  size_t t = (size_t)blockIdx.x * 256 + threadIdx.x;   // one int4 (8 bf16) per thread
  float4 u = x4[t * 2], v = x4[t * 2 + 1];
  unsigned r0 = f2bf(u.x) | ((unsigned)f2bf(u.y) << 16);
  unsigned r1 = f2bf(u.z) | ((unsigned)f2bf(u.w) << 16);
  unsigned r2 = f2bf(v.x) | ((unsigned)f2bf(v.y) << 16);
  unsigned r3 = f2bf(v.z) | ((unsigned)f2bf(v.w) << 16);
  xb4[t] = make_int4((int)r0, (int)r1, (int)r2, (int)r3);
}

// ---------------- main: 128x128 bf16 MFMA tile + fused argmin ----------------
// grid 4096 = 512 m-tiles x 8 n-tiles (nb fastest -> spread over XCDs, L3 reuse
// of x). 256 thr / 4 waves, warp-tile 64x64. LDS ~19.5KB -> ~3 blocks/CU.
// XOR source-swizzle: LDS slot (row,g) holds k-group (g ^ ((row>>1)&3)), so
// global_load_lds stays lane-linear AND frag ds_read_b128 is <=2-way (free).
__global__ __launch_bounds__(256) void vq_main(const unsigned short* __restrict__ xb,
                                               const unsigned short* __restrict__ cbb,
                                               const float* __restrict__ c2h,
                                               float* __restrict__ cand1,
                                               float* __restrict__ cand2,
                                               int* __restrict__ candc) {
  __shared__ unsigned short As[128 * 32];   // 8 KB
  __shared__ unsigned short Bs[128 * 32];   // 8 KB
  __shared__ float red1[256], red2[256];
  __shared__ int redc[256];

  const int tid = threadIdx.x;
  const int lane = tid & 63, wv = tid >> 6;
  const int mw = wv & 1, nw = wv >> 1;
  const int c = lane & 15, q = lane >> 4;
  const int mb = blockIdx.x >> 3, nb = blockIdx.x & 7;

  const int r0 = tid >> 2, g0 = tid & 3;
  const int s0 = (r0 >> 1) & 3;                       // (r0+64) has same bits 1..2
  const size_t xrow0 = (size_t)(mb * 128 + r0) * KDIM + ((g0 ^ s0) * 8);
  const size_t crow0 = (size_t)(nb * 128 + r0) * KDIM + ((g0 ^ s0) * 8);

  f32x4 acc[4][4];
#pragma unroll
  for (int i = 0; i < 4; ++i)
#pragma unroll
    for (int j = 0; j < 4; ++j) acc[i][j] = (f32x4){0.f, 0.f, 0.f, 0.f};

  for (int ko = 0; ko < 16; ++ko) {
    const int k0 = ko * 32;
    async16(xb + xrow0 + k0,              &As[tid * 8]);
    async16(xb + xrow0 + 64 * KDIM + k0,  &As[2048 + tid * 8]);
    async16(cbb + crow0 + k0,             &Bs[tid * 8]);
    async16(cbb + crow0 + 64 * KDIM + k0, &Bs[2048 + tid * 8]);
    __syncthreads();                                   // loads -> LDS done
    short8 a[4], b[4];
#pragma unroll
    for (int i = 0; i < 4; ++i) {
      int mr = mw * 64 + i * 16 + c;
      a[i] = *(const short8*)&As[mr * 32 + ((q ^ ((mr >> 1) & 3)) * 8)];
    }
#pragma unroll
    for (int j = 0; j < 4; ++j) {
      int nr = nw * 64 + j * 16 + c;
      b[j] = *(const short8*)&Bs[nr * 32 + ((q ^ ((nr >> 1) & 3)) * 8)];
    }
#pragma unroll
    for (int i = 0; i < 4; ++i)
#pragma unroll
      for (int j = 0; j < 4; ++j)
        acc[i][j] = __builtin_amdgcn_mfma_f32_16x16x32_bf16(a[i], b[j], acc[i][j], 0, 0, 0);
    __syncthreads();                                   // frag reads done before restage
  }

  // epilogue: s = 0.5||c||^2 - dot ; per-query (min1,min2,argmin) over 128 codes
  float mn1[4][4], mn2[4][4];
  int mcol[4][4];
#pragma unroll
  for (int i = 0; i < 4; ++i)
#pragma unroll
    for (int r = 0; r < 4; ++r) { mn1[i][r] = 1e30f; mn2[i][r] = 1e30f; mcol[i][r] = 0; }
#pragma unroll
  for (int j = 0; j < 4; ++j) {
    int colb = nb * 128 + nw * 64 + j * 16 + c;        // global code id
    float c2v = c2h[colb];
#pragma unroll
    for (int i = 0; i < 4; ++i)
#pragma unroll
      for (int r = 0; r < 4; ++r) {
        float sv = c2v - acc[i][j][r];
        float hi = fmaxf(sv, mn1[i][r]);
        mn2[i][r] = fminf(mn2[i][r], hi);
        bool lt = sv < mn1[i][r];
        mn1[i][r] = lt ? sv : mn1[i][r];
        mcol[i][r] = lt ? colb : mcol[i][r];
      }
  }
#pragma unroll
  for (int m = 1; m < 16; m <<= 1) {                   // merge 16 col-lanes
#pragma unroll
    for (int i = 0; i < 4; ++i)
#pragma unroll
      for (int r = 0; r < 4; ++r) {
        float o1 = __shfl_xor(mn1[i][r], m);
        float o2 = __shfl_xor(mn2[i][r], m);
        int   oc = __shfl_xor(mcol[i][r], m);
        float hi = fmaxf(o1, mn1[i][r]);
        mn2[i][r] = fminf(fminf(mn2[i][r], o2), hi);
        bool lt = o1 < mn1[i][r];
        mn1[i][r] = lt ? o1 : mn1[i][r];
        mcol[i][r] = lt ? oc : mcol[i][r];
      }
  }
  if (c == 0) {
#pragma unroll
    for (int i = 0; i < 4; ++i)
#pragma unroll
      for (int r = 0; r < 4; ++r) {
        int rb = mw * 64 + i * 16 + q * 4 + r;         // C/D row = q*4+reg
        red1[rb * 2 + nw] = mn1[i][r];
        red2[rb * 2 + nw] = mn2[i][r];
        redc[rb * 2 + nw] = mcol[i][r];
      }
  }
  __syncthreads();
  if (tid < 128) {
    float b1 = red1[tid * 2], b2 = red2[tid * 2];
    int bc = redc[tid * 2];
    float o1 = red1[tid * 2 + 1], o2 = red2[tid * 2 + 1];
    int oc = redc[tid * 2 + 1];
    float hi = fmaxf(o1, b1);
    b2 = fminf(fminf(b2, o2), hi);
    if (o1 < b1) { b1 = o1; bc = oc; }
    size_t qg = (size_t)(mb * 128 + tid) * 8 + nb;
    cand1[qg] = b1; cand2[qg] = b2; candc[qg] = bc;
  }
}

// ---------------- reduce: merge 8 candidates/query, flag near-ties ----------------
__global__ __launch_bounds__(256) void vq_reduce(const float4* __restrict__ c1,
                                                 const float4* __restrict__ c2,
                                                 const int4* __restrict__ cc,
                                                 int* __restrict__ idx,
                                                 int* __restrict__ list,
                                                 int* __restrict__ counter) {
  int qg = blockIdx.x * 256 + threadIdx.x;
  float4 a1 = c1[qg * 2], b1v = c1[qg * 2 + 1];
  float4 a2 = c2[qg * 2], b2v = c2[qg * 2 + 1];
  int4 ai = cc[qg * 2], bi = cc[qg * 2 + 1];
  float m1[8] = {a1.x, a1.y, a1.z, a1.w, b1v.x, b1v.y, b1v.z, b1v.w};
  float m2[8] = {a2.x, a2.y, a2.z, a2.w, b2v.x, b2v.y, b2v.z, b2v.w};
  int mc[8] = {ai.x, ai.y, ai.z, ai.w, bi.x, bi.y, bi.z, bi.w};
  float g1 = m1[0], g2 = m2[0];
  int gc = mc[0];
#pragma unroll
  for (int k = 1; k < 8; ++k) {
    float hi = fmaxf(m1[k], g1);
    g2 = fminf(fminf(g2, m2[k]), hi);
    if (m1[k] < g1) { g1 = m1[k]; gc = mc[k]; }
  }
  idx[qg] = gc;
  if (g2 - g1 < TAU_S) { int p = atomicAdd(counter, 1); list[p] = qg; }
}

// ---------------- refine: exact fp64 re-scan, coalesced ----------------
// One block (4 waves) per flagged query; wave reads a full 2KB codebook row
// per code (coalesced), per-lane fp64 partial, butterfly sum.
__global__ __launch_bounds__(256) void vq_refine(const float* __restrict__ x,
                                                 const float* __restrict__ cb,
                                                 const double* __restrict__ c2d,
                                                 const int* __restrict__ list,
                                                 const int* __restrict__ counter,
                                                 int* __restrict__ idx) {
  __shared__ double rv[4];
  __shared__ int rc[4];
  const int cnt = counter[0];
  const int tid = threadIdx.x, lane = tid & 63, wv = tid >> 6;
  const float4* cb4 = (const float4*)cb;
  for (int qi = blockIdx.x; qi < cnt; qi += gridDim.x) {
    const int query = list[qi];
    const float* xr = x + (size_t)query * KDIM + lane * 8;
    float4 u = *(const float4*)xr;
    float4 v = *(const float4*)(xr + 4);
    double xd0 = u.x, xd1 = u.y, xd2 = u.z, xd3 = u.w;
    double xd4 = v.x, xd5 = v.y, xd6 = v.z, xd7 = v.w;
    double bb = 1e300;
    int bci = 0;
#pragma unroll 2
    for (int cc = 0; cc < 256; ++cc) {
      int code = wv * 256 + cc;
      float4 p = cb4[(size_t)code * 128 + lane * 2];
      float4 r = cb4[(size_t)code * 128 + lane * 2 + 1];
      double s = xd0 * p.x + xd1 * p.y + xd2 * p.z + xd3 * p.w +
                 xd4 * r.x + xd5 * r.y + xd6 * r.z + xd7 * r.w;
#pragma unroll
      for (int m = 1; m < 64; m <<= 1) s += __shfl_xor(s, m);
      double sc = c2d[code] - s;
      if (sc < bb) { bb = sc; bci = code; }
    }
    if (lane == 0) { rv[wv] = bb; rc[wv] = bci; }
    __syncthreads();
    if (tid == 0) {
      double b = rv[0]; int bc = rc[0];
#pragma unroll
      for (int w = 1; w < 4; ++w)
        if (rv[w] < b) { b = rv[w]; bc = rc[w]; }
      idx[query] = bc;
    }
    __syncthreads();
  }
}

// ---------------- gather: out[q] = codebook[idx[q]] ----------------
__global__ __launch_bounds__(256) void vq_gather(const float* __restrict__ cb,
                                                 const int* __restrict__ idx,
                                                 float* __restrict__ out) {
  size_t i = (size_t)blockIdx.x * 256 + threadIdx.x;   // float4 index
  int qg = (int)(i >> 7), d = (int)(i & 127);
  ((float4*)out)[i] = ((const float4*)cb)[(size_t)idx[qg] * 128 + d];
}

extern "C" void kernel_launch(void* const* d_in, const int* in_sizes, int n_in,
                              void* d_out, int out_size, void* d_ws, size_t ws_size,
                              hipStream_t stream) {
  const float* x = (const float*)d_in[0];
  const float* cb = (const float*)d_in[1];
  float* out = (float*)d_out;
  char* ws = (char*)d_ws;
  if (ws_size < WS_NEED) {
    fprintf(stderr, "vq: ws_size %zu too small (need %llu)\n", ws_size,
            (unsigned long long)WS_NEED);
    return;
  }
  unsigned short* xb = (unsigned short*)(ws + WS_XB);
  unsigned short* cbb = (unsigned short*)(ws + WS_CBB);
  float* c2h = (float*)(ws + WS_C2H);
  double* c2d = (double*)(ws + WS_C2D);
  float* cand1 = (float*)(ws + WS_CAND1);
  float* cand2 = (float*)(ws + WS_CAND2);
  int* candc = (int*)(ws + WS_CANDC);
  int* idx = (int*)(ws + WS_IDX);
  int* list = (int*)(ws + WS_LIST);
  int* counter = (int*)(ws + WS_CTR);

  hipMemsetAsync(counter, 0, 4, stream);
  vq_prep<<<256, 256, 0, stream>>>(cb, cbb, c2h, c2d);
  vq_convx<<<16384, 256, 0, stream>>>((const float4*)x, (int4*)xb);
  vq_main<<<4096, 256, 0, stream>>>(xb, cbb, c2h, cand1, cand2, candc);
  vq_reduce<<<256, 256, 0, stream>>>((const float4*)cand1, (const float4*)cand2,
                                     (const int4*)candc, idx, list, counter);
  vq_refine<<<2048, 256, 0, stream>>>(x, cb, c2d, list, counter, idx);
  vq_gather<<<32768, 256, 0, stream>>>(cb, idx, out);
}

// Round 3
// 435.948 us; speedup vs baseline: 1.6316x; 1.6316x over previous
//
#include <hip/hip_runtime.h>
#include <cstdio>

// VQ nearest-codebook, round 3.
// fp16 stage-1 MFMA (8x tighter than bf16 -> TAU 0.05, ~800 flagged) ;
// refine = lane-per-4-codes fp64 scan over transposed codebook (no shuffles
// in the inner loop) ; main double-buffered LDS.

typedef float f32x4 __attribute__((ext_vector_type(4)));
typedef _Float16 half8 __attribute__((ext_vector_type(8)));

#define KDIM 512
#define NCODES 1024
#define NQ 65536
#define TAU_S 0.05f   // bf16 passed at 0.30; fp16 err is 8x smaller -> 0.0375 scaled, 0.05 w/ margin

// ---- workspace layout (bytes) ----
#define WS_XH    0ull                         // fp16 x [65536][512]      67108864
#define WS_CBH   67108864ull                  // fp16 cb [1024][512]       1048576
#define WS_C2H   68157440ull                  // float 0.5||c||^2 [1024]
#define WS_C2D   68161536ull                  // double 0.5||c||^2 [1024]
#define WS_CAND1 68169728ull                  // float [65536][8]; REUSED as cbT after vq_reduce
#define WS_CBT   WS_CAND1                     // fp32 cbT [512][1024] = 2097152 (exact fit)
#define WS_CAND2 70266880ull                  // float  [65536][8]
#define WS_CANDC 72364032ull                  // int    [65536][8]
#define WS_IDX   74461184ull                  // int    [65536]
#define WS_LIST  74723328ull                  // int    [65536]
#define WS_CTR   74985472ull                  // int
#define WS_NEED  (WS_CTR + 4ull)

__device__ __forceinline__ unsigned short f2h(float f) {
  _Float16 h = (_Float16)f;                   // RNE
  return __builtin_bit_cast(unsigned short, h);
}

__device__ __forceinline__ void async16(const void* g, void* l) {
  __builtin_amdgcn_global_load_lds(
      (const __attribute__((address_space(1))) void*)g,
      (__attribute__((address_space(3))) void*)l, 16, 0, 0);
}

// ---------------- prep: codebook -> fp16 row-major + 0.5||c||^2 ----------------
__global__ __launch_bounds__(256) void vq_prep(const float* __restrict__ cb,
                                               unsigned short* __restrict__ cbh,
                                               float* __restrict__ c2h,
                                               double* __restrict__ c2d) {
  int lane = threadIdx.x & 63;
  int row = blockIdx.x * 4 + (threadIdx.x >> 6);
  const float4* src = (const float4*)(cb + (size_t)row * KDIM);
  float4 u = src[lane * 2], v = src[lane * 2 + 1];
  double p = (double)u.x * u.x + (double)u.y * u.y + (double)u.z * u.z + (double)u.w * u.w +
             (double)v.x * v.x + (double)v.y * v.y + (double)v.z * v.z + (double)v.w * v.w;
#pragma unroll
  for (int m = 1; m < 64; m <<= 1) p += __shfl_xor(p, m);
  if (lane == 0) { c2h[row] = (float)(0.5 * p); c2d[row] = 0.5 * p; }
  unsigned r0 = f2h(u.x) | ((unsigned)f2h(u.y) << 16);
  unsigned r1 = f2h(u.z) | ((unsigned)f2h(u.w) << 16);
  unsigned r2 = f2h(v.x) | ((unsigned)f2h(v.y) << 16);
  unsigned r3 = f2h(v.z) | ((unsigned)f2h(v.w) << 16);
  *(int4*)(cbh + (size_t)row * KDIM + lane * 8) = make_int4((int)r0, (int)r1, (int)r2, (int)r3);
}

// ---------------- convx: x fp32 -> fp16 ----------------
__global__ __launch_bounds__(256) void vq_convx(const float4* __restrict__ x4,
                                                int4* __restrict__ xh4) {
  size_t t = (size_t)blockIdx.x * 256 + threadIdx.x;
  float4 u = x4[t * 2], v = x4[t * 2 + 1];
  unsigned r0 = f2h(u.x) | ((unsigned)f2h(u.y) << 16);
  unsigned r1 = f2h(u.z) | ((unsigned)f2h(u.w) << 16);
  unsigned r2 = f2h(v.x) | ((unsigned)f2h(v.y) << 16);
  unsigned r3 = f2h(v.z) | ((unsigned)f2h(v.w) << 16);
  xh4[t] = make_int4((int)r0, (int)r1, (int)r2, (int)r3);
}

// ---------------- main: 128x128 fp16 MFMA tile + fused argmin ----------------
// grid 4096 = 512 m-tiles x 8 n-tiles (nb == XCD id -> B tile L2-resident per
// XCD; A tile shared via L3). 256 thr / 4 waves, 64x64 warp tiles.
// Double-buffered LDS (2x16KB): prefetch next BK=32 slab after barrier #1,
// drained by barrier #2 -> load latency overlapped with the MFMA window.
__global__ __launch_bounds__(256) void vq_main(const unsigned short* __restrict__ xh,
                                               const unsigned short* __restrict__ cbh,
                                               const float* __restrict__ c2h,
                                               float* __restrict__ cand1,
                                               float* __restrict__ cand2,
                                               int* __restrict__ candc) {
  __shared__ unsigned short As[2][128 * 32];  // 2 x 8 KB
  __shared__ unsigned short Bs[2][128 * 32];  // 2 x 8 KB
  __shared__ float red1[256], red2[256];
  __shared__ int redc[256];

  const int tid = threadIdx.x;
  const int lane = tid & 63, wv = tid >> 6;
  const int mw = wv & 1, nw = wv >> 1;
  const int c = lane & 15, q = lane >> 4;
  const int mb = blockIdx.x >> 3, nb = blockIdx.x & 7;

  const int r0 = tid >> 2, g0 = tid & 3;
  const int s0 = (r0 >> 1) & 3;               // rows r0 and r0+64 share bits 1..2
  const size_t xrow0 = (size_t)(mb * 128 + r0) * KDIM + ((g0 ^ s0) * 8);
  const size_t crow0 = (size_t)(nb * 128 + r0) * KDIM + ((g0 ^ s0) * 8);

  f32x4 acc[4][4];
#pragma unroll
  for (int i = 0; i < 4; ++i)
#pragma unroll
    for (int j = 0; j < 4; ++j) acc[i][j] = (f32x4){0.f, 0.f, 0.f, 0.f};

  // prologue: stage slab 0 into buffer 0
  async16(xh + xrow0,              &As[0][tid * 8]);
  async16(xh + xrow0 + 64 * KDIM,  &As[0][2048 + tid * 8]);
  async16(cbh + crow0,             &Bs[0][tid * 8]);
  async16(cbh + crow0 + 64 * KDIM, &Bs[0][2048 + tid * 8]);

  for (int ko = 0; ko < 16; ++ko) {
    const int cur = ko & 1;
    __syncthreads();                           // buf[cur] ready
    if (ko + 1 < 16) {
      const int k0 = (ko + 1) * 32;
      async16(xh + xrow0 + k0,              &As[1 - cur][tid * 8]);
      async16(xh + xrow0 + 64 * KDIM + k0,  &As[1 - cur][2048 + tid * 8]);
      async16(cbh + crow0 + k0,             &Bs[1 - cur][tid * 8]);
      async16(cbh + crow0 + 64 * KDIM + k0, &Bs[1 - cur][2048 + tid * 8]);
    }
    half8 a[4], b[4];
#pragma unroll
    for (int i = 0; i < 4; ++i) {
      int mr = mw * 64 + i * 16 + c;
      a[i] = *(const half8*)&As[cur][mr * 32 + ((q ^ ((mr >> 1) & 3)) * 8)];
    }
#pragma unroll
    for (int j = 0; j < 4; ++j) {
      int nr = nw * 64 + j * 16 + c;
      b[j] = *(const half8*)&Bs[cur][nr * 32 + ((q ^ ((nr >> 1) & 3)) * 8)];
    }
#pragma unroll
    for (int i = 0; i < 4; ++i)
#pragma unroll
      for (int j = 0; j < 4; ++j)
        acc[i][j] = __builtin_amdgcn_mfma_f32_16x16x32_f16(a[i], b[j], acc[i][j], 0, 0, 0);
    __syncthreads();                           // frag reads done; prefetch drained here
  }

  // epilogue: s = 0.5||c||^2 - dot ; per-query (min1,min2,argmin) over 128 codes
  float mn1[4][4], mn2[4][4];
  int mcol[4][4];
#pragma unroll
  for (int i = 0; i < 4; ++i)
#pragma unroll
    for (int r = 0; r < 4; ++r) { mn1[i][r] = 1e30f; mn2[i][r] = 1e30f; mcol[i][r] = 0; }
#pragma unroll
  for (int j = 0; j < 4; ++j) {
    int colb = nb * 128 + nw * 64 + j * 16 + c;
    float c2v = c2h[colb];
#pragma unroll
    for (int i = 0; i < 4; ++i)
#pragma unroll
      for (int r = 0; r < 4; ++r) {
        float sv = c2v - acc[i][j][r];
        float hi = fmaxf(sv, mn1[i][r]);
        mn2[i][r] = fminf(mn2[i][r], hi);
        bool lt = sv < mn1[i][r];
        mn1[i][r] = lt ? sv : mn1[i][r];
        mcol[i][r] = lt ? colb : mcol[i][r];
      }
  }
#pragma unroll
  for (int m = 1; m < 16; m <<= 1) {
#pragma unroll
    for (int i = 0; i < 4; ++i)
#pragma unroll
      for (int r = 0; r < 4; ++r) {
        float o1 = __shfl_xor(mn1[i][r], m);
        float o2 = __shfl_xor(mn2[i][r], m);
        int   oc = __shfl_xor(mcol[i][r], m);
        float hi = fmaxf(o1, mn1[i][r]);
        mn2[i][r] = fminf(fminf(mn2[i][r], o2), hi);
        bool lt = o1 < mn1[i][r];
        mn1[i][r] = lt ? o1 : mn1[i][r];
        mcol[i][r] = lt ? oc : mcol[i][r];
      }
  }
  if (c == 0) {
#pragma unroll
    for (int i = 0; i < 4; ++i)
#pragma unroll
      for (int r = 0; r < 4; ++r) {
        int rb = mw * 64 + i * 16 + q * 4 + r;  // C/D row = q*4+reg
        red1[rb * 2 + nw] = mn1[i][r];
        red2[rb * 2 + nw] = mn2[i][r];
        redc[rb * 2 + nw] = mcol[i][r];
      }
  }
  __syncthreads();
  if (tid < 128) {
    float b1 = red1[tid * 2], b2 = red2[tid * 2];
    int bc = redc[tid * 2];
    float o1 = red1[tid * 2 + 1], o2 = red2[tid * 2 + 1];
    int oc = redc[tid * 2 + 1];
    float hi = fmaxf(o1, b1);
    b2 = fminf(fminf(b2, o2), hi);
    if (o1 < b1) { b1 = o1; bc = oc; }
    size_t qg = (size_t)(mb * 128 + tid) * 8 + nb;
    cand1[qg] = b1; cand2[qg] = b2; candc[qg] = bc;
  }
}

// ---------------- reduce: merge 8 candidates/query, flag near-ties ----------------
__global__ __launch_bounds__(256) void vq_reduce(const float4* __restrict__ c1,
                                                 const float4* __restrict__ c2,
                                                 const int4* __restrict__ cc,
                                                 int* __restrict__ idx,
                                                 int* __restrict__ list,
                                                 int* __restrict__ counter) {
  int qg = blockIdx.x * 256 + threadIdx.x;
  float4 a1 = c1[qg * 2], b1v = c1[qg * 2 + 1];
  float4 a2 = c2[qg * 2], b2v = c2[qg * 2 + 1];
  int4 ai = cc[qg * 2], bi = cc[qg * 2 + 1];
  float m1[8] = {a1.x, a1.y, a1.z, a1.w, b1v.x, b1v.y, b1v.z, b1v.w};
  float m2[8] = {a2.x, a2.y, a2.z, a2.w, b2v.x, b2v.y, b2v.z, b2v.w};
  int mc[8] = {ai.x, ai.y, ai.z, ai.w, bi.x, bi.y, bi.z, bi.w};
  float g1 = m1[0], g2 = m2[0];
  int gc = mc[0];
#pragma unroll
  for (int k = 1; k < 8; ++k) {
    float hi = fmaxf(m1[k], g1);
    g2 = fminf(fminf(g2, m2[k]), hi);
    if (m1[k] < g1) { g1 = m1[k]; gc = mc[k]; }
  }
  idx[qg] = gc;
  if (g2 - g1 < TAU_S) { int p = atomicAdd(counter, 1); list[p] = qg; }
}

// ---------------- trans: cb [1024][512] -> cbT [512][1024] (fp32) ----------------
// runs AFTER vq_reduce; cbT lives in the (now dead) cand1 region.
__global__ __launch_bounds__(256) void vq_trans(const float4* __restrict__ cb4,
                                                float4* __restrict__ cbT4) {
  __shared__ float t[64][65];
  const int bc = blockIdx.x >> 3, bk = blockIdx.x & 7;
  const int c0 = bc * 64, k0 = bk * 64;
  const int r = threadIdx.x >> 4, q4 = threadIdx.x & 15;
#pragma unroll
  for (int p = 0; p < 4; ++p) {
    int row = p * 16 + r;
    float4 v = cb4[(size_t)(c0 + row) * 128 + (k0 >> 2) + q4];
    t[row][q4 * 4 + 0] = v.x; t[row][q4 * 4 + 1] = v.y;
    t[row][q4 * 4 + 2] = v.z; t[row][q4 * 4 + 3] = v.w;
  }
  __syncthreads();
#pragma unroll
  for (int p = 0; p < 4; ++p) {
    int kk = p * 16 + r;
    float4 v = make_float4(t[q4 * 4 + 0][kk], t[q4 * 4 + 1][kk],
                           t[q4 * 4 + 2][kk], t[q4 * 4 + 3][kk]);
    cbT4[(size_t)(k0 + kk) * 256 + (c0 >> 2) + q4] = v;
  }
}

// ---------------- refine: exact fp64 re-scan, lane-per-4-codes ----------------
// One block per flagged query. Thread t owns codes 4t..4t+3 (cbT float4).
// No cross-lane ops in the inner loop; single 64+4 reduction per query.
__global__ __launch_bounds__(256) void vq_refine(const float* __restrict__ x,
                                                 const float4* __restrict__ cbT4,
                                                 const double* __restrict__ c2d,
                                                 const int* __restrict__ list,
                                                 const int* __restrict__ counter,
                                                 int* __restrict__ idx) {
  __shared__ float xs[512];
  __shared__ double rv[4];
  __shared__ int rc[4];
  const int cnt = counter[0];
  const int tid = threadIdx.x, lane = tid & 63, wv = tid >> 6;
  for (int qi = blockIdx.x; qi < cnt; qi += gridDim.x) {
    const int query = list[qi];
    __syncthreads();
    xs[tid] = x[(size_t)query * KDIM + tid];
    xs[tid + 256] = x[(size_t)query * KDIM + tid + 256];
    __syncthreads();
    double a0 = 0, a1 = 0, a2 = 0, a3 = 0;
    const float4* xs4 = (const float4*)xs;
#pragma unroll 2
    for (int k4 = 0; k4 < 128; ++k4) {
      float4 xv = xs4[k4];
      float4 c0 = cbT4[(k4 * 4 + 0) * 256 + tid];
      float4 c1 = cbT4[(k4 * 4 + 1) * 256 + tid];
      float4 c2v = cbT4[(k4 * 4 + 2) * 256 + tid];
      float4 c3 = cbT4[(k4 * 4 + 3) * 256 + tid];
      a0 = fma((double)xv.x, (double)c0.x, a0);
      a1 = fma((double)xv.x, (double)c0.y, a1);
      a2 = fma((double)xv.x, (double)c0.z, a2);
      a3 = fma((double)xv.x, (double)c0.w, a3);
      a0 = fma((double)xv.y, (double)c1.x, a0);
      a1 = fma((double)xv.y, (double)c1.y, a1);
      a2 = fma((double)xv.y, (double)c1.z, a2);
      a3 = fma((double)xv.y, (double)c1.w, a3);
      a0 = fma((double)xv.z, (double)c2v.x, a0);
      a1 = fma((double)xv.z, (double)c2v.y, a1);
      a2 = fma((double)xv.z, (double)c2v.z, a2);
      a3 = fma((double)xv.z, (double)c2v.w, a3);
      a0 = fma((double)xv.w, (double)c3.x, a0);
      a1 = fma((double)xv.w, (double)c3.y, a1);
      a2 = fma((double)xv.w, (double)c3.z, a2);
      a3 = fma((double)xv.w, (double)c3.w, a3);
    }
    double best = c2d[tid * 4] - a0;
    int bc = tid * 4;
    double s1 = c2d[tid * 4 + 1] - a1;
    if (s1 < best) { best = s1; bc = tid * 4 + 1; }
    double s2 = c2d[tid * 4 + 2] - a2;
    if (s2 < best) { best = s2; bc = tid * 4 + 2; }
    double s3 = c2d[tid * 4 + 3] - a3;
    if (s3 < best) { best = s3; bc = tid * 4 + 3; }
#pragma unroll
    for (int m = 1; m < 64; m <<= 1) {
      double o = __shfl_xor(best, m);
      int oc = __shfl_xor(bc, m);
      if (o < best) { best = o; bc = oc; }
    }
    if (lane == 0) { rv[wv] = best; rc[wv] = bc; }
    __syncthreads();
    if (tid == 0) {
      double b = rv[0]; int bci = rc[0];
#pragma unroll
      for (int w = 1; w < 4; ++w)
        if (rv[w] < b) { b = rv[w]; bci = rc[w]; }
      idx[query] = bci;
    }
    __syncthreads();
  }
}

// ---------------- gather: out[q] = codebook[idx[q]] ----------------
__global__ __launch_bounds__(256) void vq_gather(const float* __restrict__ cb,
                                                 const int* __restrict__ idx,
                                                 float* __restrict__ out) {
  size_t i = (size_t)blockIdx.x * 256 + threadIdx.x;
  int qg = (int)(i >> 7), d = (int)(i & 127);
  ((float4*)out)[i] = ((const float4*)cb)[(size_t)idx[qg] * 128 + d];
}

extern "C" void kernel_launch(void* const* d_in, const int* in_sizes, int n_in,
                              void* d_out, int out_size, void* d_ws, size_t ws_size,
                              hipStream_t stream) {
  const float* x = (const float*)d_in[0];
  const float* cb = (const float*)d_in[1];
  float* out = (float*)d_out;
  char* ws = (char*)d_ws;
  if (ws_size < WS_NEED) {
    fprintf(stderr, "vq: ws_size %zu too small (need %llu)\n", ws_size,
            (unsigned long long)WS_NEED);
    return;
  }
  unsigned short* xh = (unsigned short*)(ws + WS_XH);
  unsigned short* cbh = (unsigned short*)(ws + WS_CBH);
  float* c2h = (float*)(ws + WS_C2H);
  double* c2d = (double*)(ws + WS_C2D);
  float* cand1 = (float*)(ws + WS_CAND1);
  float* cand2 = (float*)(ws + WS_CAND2);
  int* candc = (int*)(ws + WS_CANDC);
  float* cbT = (float*)(ws + WS_CBT);
  int* idx = (int*)(ws + WS_IDX);
  int* list = (int*)(ws + WS_LIST);
  int* counter = (int*)(ws + WS_CTR);

  hipMemsetAsync(counter, 0, 4, stream);
  vq_prep<<<256, 256, 0, stream>>>(cb, cbh, c2h, c2d);
  vq_convx<<<16384, 256, 0, stream>>>((const float4*)x, (int4*)xh);
  vq_main<<<4096, 256, 0, stream>>>(xh, cbh, c2h, cand1, cand2, candc);
  vq_reduce<<<256, 256, 0, stream>>>((const float4*)cand1, (const float4*)cand2,
                                     (const int4*)candc, idx, list, counter);
  vq_trans<<<128, 256, 0, stream>>>((const float4*)cb, (float4*)cbT);
  vq_refine<<<1024, 256, 0, stream>>>(x, (const float4*)cbT, c2d, list, counter, idx);
  vq_gather<<<32768, 256, 0, stream>>>(cb, idx, out);
}

// Round 4
// 417.684 us; speedup vs baseline: 1.7030x; 1.0437x over previous
//
#include <hip/hip_runtime.h>
#include <cstdio>

// VQ nearest-codebook, round 4.
// vq_main: 256x256 block tile (staged bytes halved: A 4x67 + B 256x1 MB
// = 524 MB), 1024 thr / 16 waves, single-barrier double-buffer (prefetch
// drains at the NEXT iteration's barrier, not same-iteration).
// fp16 stage-1 + TAU 0.05 + exact fp64 refine of flagged + gather.

typedef float f32x4 __attribute__((ext_vector_type(4)));
typedef _Float16 half8 __attribute__((ext_vector_type(8)));

#define KDIM 512
#define NCODES 1024
#define NQ 65536
#define TAU_S 0.05f   // fp16 dot err sigma ~0.009; 0.05 ~ 5.5 sigma (passed R3, absmax 0)

// ---- workspace layout (bytes) ----
#define WS_XH    0ull                         // fp16 x [65536][512]      67108864
#define WS_CBH   67108864ull                  // fp16 cb [1024][512]       1048576
#define WS_C2H   68157440ull                  // float 0.5||c||^2 [1024]
#define WS_C2D   68161536ull                  // double 0.5||c||^2 [1024]
#define WS_CAND1 68169728ull                  // float [65536][4] (1 MB); +CAND2 reused as cbT
#define WS_CBT   WS_CAND1                     // fp32 cbT [512][1024] = 2 MB (spans CAND1+CAND2)
#define WS_CAND2 69218304ull                  // float [65536][4] (1 MB)
#define WS_CANDC 70266880ull                  // int   [65536][4] (1 MB)
#define WS_IDX   71315456ull                  // int   [65536]
#define WS_LIST  71577600ull                  // int   [65536]
#define WS_CTR   71839744ull                  // int
#define WS_NEED  (WS_CTR + 4ull)

__device__ __forceinline__ unsigned short f2h(float f) {
  _Float16 h = (_Float16)f;                   // RNE
  return __builtin_bit_cast(unsigned short, h);
}

__device__ __forceinline__ void async16(const void* g, void* l) {
  __builtin_amdgcn_global_load_lds(
      (const __attribute__((address_space(1))) void*)g,
      (__attribute__((address_space(3))) void*)l, 16, 0, 0);
}

// ---------------- prep: codebook -> fp16 row-major + 0.5||c||^2 ----------------
__global__ __launch_bounds__(256) void vq_prep(const float* __restrict__ cb,
                                               unsigned short* __restrict__ cbh,
                                               float* __restrict__ c2h,
                                               double* __restrict__ c2d) {
  int lane = threadIdx.x & 63;
  int row = blockIdx.x * 4 + (threadIdx.x >> 6);
  const float4* src = (const float4*)(cb + (size_t)row * KDIM);
  float4 u = src[lane * 2], v = src[lane * 2 + 1];
  double p = (double)u.x * u.x + (double)u.y * u.y + (double)u.z * u.z + (double)u.w * u.w +
             (double)v.x * v.x + (double)v.y * v.y + (double)v.z * v.z + (double)v.w * v.w;
#pragma unroll
  for (int m = 1; m < 64; m <<= 1) p += __shfl_xor(p, m);
  if (lane == 0) { c2h[row] = (float)(0.5 * p); c2d[row] = 0.5 * p; }
  unsigned r0 = f2h(u.x) | ((unsigned)f2h(u.y) << 16);
  unsigned r1 = f2h(u.z) | ((unsigned)f2h(u.w) << 16);
  unsigned r2 = f2h(v.x) | ((unsigned)f2h(v.y) << 16);
  unsigned r3 = f2h(v.z) | ((unsigned)f2h(v.w) << 16);
  *(int4*)(cbh + (size_t)row * KDIM + lane * 8) = make_int4((int)r0, (int)r1, (int)r2, (int)r3);
}

// ---------------- convx: x fp32 -> fp16 ----------------
__global__ __launch_bounds__(256) void vq_convx(const float4* __restrict__ x4,
                                                int4* __restrict__ xh4) {
  size_t t = (size_t)blockIdx.x * 256 + threadIdx.x;
  float4 u = x4[t * 2], v = x4[t * 2 + 1];
  unsigned r0 = f2h(u.x) | ((unsigned)f2h(u.y) << 16);
  unsigned r1 = f2h(u.z) | ((unsigned)f2h(u.w) << 16);
  unsigned r2 = f2h(v.x) | ((unsigned)f2h(v.y) << 16);
  unsigned r3 = f2h(v.z) | ((unsigned)f2h(v.w) << 16);
  xh4[t] = make_int4((int)r0, (int)r1, (int)r2, (int)r3);
}

// ---------------- main: 256x256 fp16 MFMA tile + fused argmin ----------------
// grid 1024 = 256 m-tiles x 4 n-tiles (nb = blk&3; XCD = blk&7 sees one nb ->
// its 256 KB B tile stays L2-resident; A tile shared across XCDs via L3).
// 1024 thr / 16 waves as 4x4 of 64x64 warp tiles. LDS 64 KB: As[2]/Bs[2] of
// 16 KB. ONE barrier per ko: prefetch issued after barrier ko lands by
// barrier ko+1 (full-iteration window, ~850 cyc/SIMD of MFMA+ds_read).
__global__ __launch_bounds__(1024, 4) void vq_main(const unsigned short* __restrict__ xh,
                                                   const unsigned short* __restrict__ cbh,
                                                   const float* __restrict__ c2h,
                                                   float* __restrict__ cand1,
                                                   float* __restrict__ cand2,
                                                   int* __restrict__ candc) {
  __shared__ char pool[65536];
  unsigned short* As0 = (unsigned short*)pool;             // [2][256*32] halfs
  unsigned short* Bs0 = (unsigned short*)(pool + 32768);
  float* red1 = (float*)pool;                              // alias (post-loop)
  float* red2 = (float*)(pool + 4096);
  int*   redc = (int*)(pool + 8192);

  const int tid = threadIdx.x;
  const int lane = tid & 63, wv = tid >> 6;
  const int mw = wv & 3, nw = wv >> 2;
  const int c = lane & 15, q = lane >> 4;
  const int mb = blockIdx.x >> 2, nb = blockIdx.x & 3;

  const int r0 = tid >> 2, g0 = tid & 3;
  const int s0 = (r0 >> 1) & 3;
  const size_t xrow0 = (size_t)(mb * 256 + r0) * KDIM + ((g0 ^ s0) * 8);
  const size_t crow0 = (size_t)(nb * 256 + r0) * KDIM + ((g0 ^ s0) * 8);

  f32x4 acc[4][4];
#pragma unroll
  for (int i = 0; i < 4; ++i)
#pragma unroll
    for (int j = 0; j < 4; ++j) acc[i][j] = (f32x4){0.f, 0.f, 0.f, 0.f};

  // prologue: stage slab 0 into buffer 0 (one async16 per thread per slab)
  async16(xh + xrow0,  &As0[tid * 8]);
  async16(cbh + crow0, &Bs0[tid * 8]);

  for (int ko = 0; ko < 16; ++ko) {
    const int cur = ko & 1;
    __syncthreads();                           // drains prev prefetch (vmcnt0) + WAR
    if (ko + 1 < 16) {
      const int k0 = (ko + 1) * 32;
      async16(xh + xrow0 + k0,  &As0[(1 - cur) * 8192 + tid * 8]);
      async16(cbh + crow0 + k0, &Bs0[(1 - cur) * 8192 + tid * 8]);
    }
    const unsigned short* A = &As0[cur * 8192];
    const unsigned short* B = &Bs0[cur * 8192];
    half8 a[4], b[4];
#pragma unroll
    for (int i = 0; i < 4; ++i) {
      int mr = mw * 64 + i * 16 + c;
      a[i] = *(const half8*)&A[mr * 32 + ((q ^ ((mr >> 1) & 3)) * 8)];
    }
#pragma unroll
    for (int j = 0; j < 4; ++j) {
      int nr = nw * 64 + j * 16 + c;
      b[j] = *(const half8*)&B[nr * 32 + ((q ^ ((nr >> 1) & 3)) * 8)];
    }
#pragma unroll
    for (int i = 0; i < 4; ++i)
#pragma unroll
      for (int j = 0; j < 4; ++j)
        acc[i][j] = __builtin_amdgcn_mfma_f32_16x16x32_f16(a[i], b[j], acc[i][j], 0, 0, 0);
  }
  // NOTE: no bottom barrier; last iter reads buf1 only, red1/2/c alias buf0's
  // As region and are only touched by threads that finished their own reads.

  // epilogue: s = 0.5||c||^2 - dot ; per-query (min1,min2,argmin) over 256 codes
  float mn1[4][4], mn2[4][4];
  int mcol[4][4];
#pragma unroll
  for (int i = 0; i < 4; ++i)
#pragma unroll
    for (int r = 0; r < 4; ++r) { mn1[i][r] = 1e30f; mn2[i][r] = 1e30f; mcol[i][r] = 0; }
#pragma unroll
  for (int j = 0; j < 4; ++j) {
    int colb = nb * 256 + nw * 64 + j * 16 + c;
    float c2v = c2h[colb];
#pragma unroll
    for (int i = 0; i < 4; ++i)
#pragma unroll
      for (int r = 0; r < 4; ++r) {
        float sv = c2v - acc[i][j][r];
        float hi = fmaxf(sv, mn1[i][r]);
        mn2[i][r] = fminf(mn2[i][r], hi);
        bool lt = sv < mn1[i][r];
        mn1[i][r] = lt ? sv : mn1[i][r];
        mcol[i][r] = lt ? colb : mcol[i][r];
      }
  }
#pragma unroll
  for (int m = 1; m < 16; m <<= 1) {
#pragma unroll
    for (int i = 0; i < 4; ++i)
#pragma unroll
      for (int r = 0; r < 4; ++r) {
        float o1 = __shfl_xor(mn1[i][r], m);
        float o2 = __shfl_xor(mn2[i][r], m);
        int   oc = __shfl_xor(mcol[i][r], m);
        float hi = fmaxf(o1, mn1[i][r]);
        mn2[i][r] = fminf(fminf(mn2[i][r], o2), hi);
        bool lt = o1 < mn1[i][r];
        mn1[i][r] = lt ? o1 : mn1[i][r];
        mcol[i][r] = lt ? oc : mcol[i][r];
      }
  }
  if (c == 0) {
#pragma unroll
    for (int i = 0; i < 4; ++i)
#pragma unroll
      for (int r = 0; r < 4; ++r) {
        int rb = mw * 64 + i * 16 + q * 4 + r;  // C/D row = q*4+reg; rb in 0..255
        red1[rb * 4 + nw] = mn1[i][r];
        red2[rb * 4 + nw] = mn2[i][r];
        redc[rb * 4 + nw] = mcol[i][r];
      }
  }
  __syncthreads();
  if (tid < 256) {
    float b1 = red1[tid * 4], b2 = red2[tid * 4];
    int bc = redc[tid * 4];
#pragma unroll
    for (int w = 1; w < 4; ++w) {
      float o1 = red1[tid * 4 + w], o2 = red2[tid * 4 + w];
      int oc = redc[tid * 4 + w];
      float hi = fmaxf(o1, b1);
      b2 = fminf(fminf(b2, o2), hi);
      if (o1 < b1) { b1 = o1; bc = oc; }
    }
    size_t qg = (size_t)(mb * 256 + tid) * 4 + nb;
    cand1[qg] = b1; cand2[qg] = b2; candc[qg] = bc;
  }
}

// ---------------- reduce: merge 4 candidates/query, flag near-ties ----------------
__global__ __launch_bounds__(256) void vq_reduce(const float4* __restrict__ c1,
                                                 const float4* __restrict__ c2,
                                                 const int4* __restrict__ cc,
                                                 int* __restrict__ idx,
                                                 int* __restrict__ list,
                                                 int* __restrict__ counter) {
  int qg = blockIdx.x * 256 + threadIdx.x;
  float4 a1 = c1[qg];
  float4 a2 = c2[qg];
  int4 ai = cc[qg];
  float m1[4] = {a1.x, a1.y, a1.z, a1.w};
  float m2[4] = {a2.x, a2.y, a2.z, a2.w};
  int mc[4] = {ai.x, ai.y, ai.z, ai.w};
  float g1 = m1[0], g2 = m2[0];
  int gc = mc[0];
#pragma unroll
  for (int k = 1; k < 4; ++k) {
    float hi = fmaxf(m1[k], g1);
    g2 = fminf(fminf(g2, m2[k]), hi);
    if (m1[k] < g1) { g1 = m1[k]; gc = mc[k]; }
  }
  idx[qg] = gc;
  if (g2 - g1 < TAU_S) { int p = atomicAdd(counter, 1); list[p] = qg; }
}

// ---------------- trans: cb [1024][512] -> cbT [512][1024] (fp32) ----------------
__global__ __launch_bounds__(256) void vq_trans(const float4* __restrict__ cb4,
                                                float4* __restrict__ cbT4) {
  __shared__ float t[64][65];
  const int bc = blockIdx.x >> 3, bk = blockIdx.x & 7;
  const int c0 = bc * 64, k0 = bk * 64;
  const int r = threadIdx.x >> 4, q4 = threadIdx.x & 15;
#pragma unroll
  for (int p = 0; p < 4; ++p) {
    int row = p * 16 + r;
    float4 v = cb4[(size_t)(c0 + row) * 128 + (k0 >> 2) + q4];
    t[row][q4 * 4 + 0] = v.x; t[row][q4 * 4 + 1] = v.y;
    t[row][q4 * 4 + 2] = v.z; t[row][q4 * 4 + 3] = v.w;
  }
  __syncthreads();
#pragma unroll
  for (int p = 0; p < 4; ++p) {
    int kk = p * 16 + r;
    float4 v = make_float4(t[q4 * 4 + 0][kk], t[q4 * 4 + 1][kk],
                           t[q4 * 4 + 2][kk], t[q4 * 4 + 3][kk]);
    cbT4[(size_t)(k0 + kk) * 256 + (c0 >> 2) + q4] = v;
  }
}

// ---------------- refine: exact fp64 re-scan, lane-per-4-codes ----------------
__global__ __launch_bounds__(256) void vq_refine(const float* __restrict__ x,
                                                 const float4* __restrict__ cbT4,
                                                 const double* __restrict__ c2d,
                                                 const int* __restrict__ list,
                                                 const int* __restrict__ counter,
                                                 int* __restrict__ idx) {
  __shared__ float xs[512];
  __shared__ double rv[4];
  __shared__ int rc[4];
  const int cnt = counter[0];
  const int tid = threadIdx.x, lane = tid & 63, wv = tid >> 6;
  for (int qi = blockIdx.x; qi < cnt; qi += gridDim.x) {
    const int query = list[qi];
    __syncthreads();
    xs[tid] = x[(size_t)query * KDIM + tid];
    xs[tid + 256] = x[(size_t)query * KDIM + tid + 256];
    __syncthreads();
    double a0 = 0, a1 = 0, a2 = 0, a3 = 0;
    const float4* xs4 = (const float4*)xs;
#pragma unroll 4
    for (int k4 = 0; k4 < 128; ++k4) {
      float4 xv = xs4[k4];
      float4 c0 = cbT4[(k4 * 4 + 0) * 256 + tid];
      float4 c1 = cbT4[(k4 * 4 + 1) * 256 + tid];
      float4 c2v = cbT4[(k4 * 4 + 2) * 256 + tid];
      float4 c3 = cbT4[(k4 * 4 + 3) * 256 + tid];
      a0 = fma((double)xv.x, (double)c0.x, a0);
      a1 = fma((double)xv.x, (double)c0.y, a1);
      a2 = fma((double)xv.x, (double)c0.z, a2);
      a3 = fma((double)xv.x, (double)c0.w, a3);
      a0 = fma((double)xv.y, (double)c1.x, a0);
      a1 = fma((double)xv.y, (double)c1.y, a1);
      a2 = fma((double)xv.y, (double)c1.z, a2);
      a3 = fma((double)xv.y, (double)c1.w, a3);
      a0 = fma((double)xv.z, (double)c2v.x, a0);
      a1 = fma((double)xv.z, (double)c2v.y, a1);
      a2 = fma((double)xv.z, (double)c2v.z, a2);
      a3 = fma((double)xv.z, (double)c2v.w, a3);
      a0 = fma((double)xv.w, (double)c3.x, a0);
      a1 = fma((double)xv.w, (double)c3.y, a1);
      a2 = fma((double)xv.w, (double)c3.z, a2);
      a3 = fma((double)xv.w, (double)c3.w, a3);
    }
    double best = c2d[tid * 4] - a0;
    int bc = tid * 4;
    double s1 = c2d[tid * 4 + 1] - a1;
    if (s1 < best) { best = s1; bc = tid * 4 + 1; }
    double s2 = c2d[tid * 4 + 2] - a2;
    if (s2 < best) { best = s2; bc = tid * 4 + 2; }
    double s3 = c2d[tid * 4 + 3] - a3;
    if (s3 < best) { best = s3; bc = tid * 4 + 3; }
#pragma unroll
    for (int m = 1; m < 64; m <<= 1) {
      double o = __shfl_xor(best, m);
      int oc = __shfl_xor(bc, m);
      if (o < best) { best = o; bc = oc; }
    }
    if (lane == 0) { rv[wv] = best; rc[wv] = bc; }
    __syncthreads();
    if (tid == 0) {
      double b = rv[0]; int bci = rc[0];
#pragma unroll
      for (int w = 1; w < 4; ++w)
        if (rv[w] < b) { b = rv[w]; bci = rc[w]; }
      idx[query] = bci;
    }
    __syncthreads();
  }
}

// ---------------- gather: out[q] = codebook[idx[q]] ----------------
__global__ __launch_bounds__(256) void vq_gather(const float* __restrict__ cb,
                                                 const int* __restrict__ idx,
                                                 float* __restrict__ out) {
  size_t i = (size_t)blockIdx.x * 256 + threadIdx.x;
  int qg = (int)(i >> 7), d = (int)(i & 127);
  ((float4*)out)[i] = ((const float4*)cb)[(size_t)idx[qg] * 128 + d];
}

extern "C" void kernel_launch(void* const* d_in, const int* in_sizes, int n_in,
                              void* d_out, int out_size, void* d_ws, size_t ws_size,
                              hipStream_t stream) {
  const float* x = (const float*)d_in[0];
  const float* cb = (const float*)d_in[1];
  float* out = (float*)d_out;
  char* ws = (char*)d_ws;
  if (ws_size < WS_NEED) {
    fprintf(stderr, "vq: ws_size %zu too small (need %llu)\n", ws_size,
            (unsigned long long)WS_NEED);
    return;
  }
  unsigned short* xh = (unsigned short*)(ws + WS_XH);
  unsigned short* cbh = (unsigned short*)(ws + WS_CBH);
  float* c2h = (float*)(ws + WS_C2H);
  double* c2d = (double*)(ws + WS_C2D);
  float* cand1 = (float*)(ws + WS_CAND1);
  float* cand2 = (float*)(ws + WS_CAND2);
  int* candc = (int*)(ws + WS_CANDC);
  float* cbT = (float*)(ws + WS_CBT);
  int* idx = (int*)(ws + WS_IDX);
  int* list = (int*)(ws + WS_LIST);
  int* counter = (int*)(ws + WS_CTR);

  hipMemsetAsync(counter, 0, 4, stream);
  vq_prep<<<256, 256, 0, stream>>>(cb, cbh, c2h, c2d);
  vq_convx<<<16384, 256, 0, stream>>>((const float4*)x, (int4*)xh);
  vq_main<<<1024, 1024, 0, stream>>>(xh, cbh, c2h, cand1, cand2, candc);
  vq_reduce<<<256, 256, 0, stream>>>((const float4*)cand1, (const float4*)cand2,
                                     (const int4*)candc, idx, list, counter);
  vq_trans<<<128, 256, 0, stream>>>((const float4*)cb, (float4*)cbT);
  vq_refine<<<2048, 256, 0, stream>>>(x, (const float4*)cbT, c2d, list, counter, idx);
  vq_gather<<<32768, 256, 0, stream>>>(cb, idx, out);
}